// Round 1
// baseline (153.088 us; speedup 1.0000x reference)
//
#include <hip/hip_runtime.h>

#define BROWS 8192
#define TLEN  1024

// One block per row. 256 threads x 4 elements = 1024 = TLEN.
__global__ __launch_bounds__(256) void row_reduce_kernel(
    const int*   __restrict__ seq,
    const float* __restrict__ logp,
    const float* __restrict__ value,
    const float* __restrict__ reward,
    double*      __restrict__ row_sum,
    double*      __restrict__ row_cnt)
{
    const int b   = blockIdx.x;
    const int tid = threadIdx.x;
    const int lane = tid & 63;
    const int wave = tid >> 6;

    const size_t rowoff = (size_t)b * TLEN;
    const int4*   s4 = (const int4*)  (seq    + rowoff);
    const float4* l4 = (const float4*)(logp   + rowoff);
    const float4* v4 = (const float4*)(value  + rowoff);
    const float4* r4 = (const float4*)(reward + rowoff);

    const int4   s = s4[tid];
    const float4 l = l4[tid];
    const float4 v = v4[tid];
    const float4 r = r4[tid];

    const int base = tid * 4;

    // Local first-zero index among this thread's 4 tokens (TLEN = "none").
    int fz = TLEN;
    if (s.w == 0) fz = base + 3;
    if (s.z == 0) fz = base + 2;
    if (s.y == 0) fz = base + 1;
    if (s.x == 0) fz = base + 0;

    // Wave-wide min (64 lanes).
    #pragma unroll
    for (int off = 32; off > 0; off >>= 1)
        fz = min(fz, __shfl_down(fz, off, 64));

    __shared__ int    lds_fz[4];
    __shared__ double lds_sum[4];
    if (lane == 0) lds_fz[wave] = fz;
    __syncthreads();
    const int block_fz = min(min(lds_fz[0], lds_fz[1]),
                             min(lds_fz[2], lds_fz[3]));

    // Products: -logp * (reward - value); include iff t <= fz (mask semantics:
    // mask[0]=1 always; mask[t]= no zero in [0..t-1]  <=>  t <= fz).
    double acc = 0.0;
    if (base + 0 <= block_fz) acc += (double)(-l.x * (r.x - v.x));
    if (base + 1 <= block_fz) acc += (double)(-l.y * (r.y - v.y));
    if (base + 2 <= block_fz) acc += (double)(-l.z * (r.z - v.z));
    if (base + 3 <= block_fz) acc += (double)(-l.w * (r.w - v.w));

    // Wave-wide double sum.
    #pragma unroll
    for (int off = 32; off > 0; off >>= 1)
        acc += __shfl_down(acc, off, 64);

    if (lane == 0) lds_sum[wave] = acc;
    __syncthreads();
    if (tid == 0) {
        row_sum[b] = lds_sum[0] + lds_sum[1] + lds_sum[2] + lds_sum[3];
        row_cnt[b] = (double)min(block_fz + 1, TLEN);
    }
}

// Single block: reduce 8192 row partials deterministically, write scalar.
__global__ __launch_bounds__(256) void final_reduce_kernel(
    const double* __restrict__ row_sum,
    const double* __restrict__ row_cnt,
    float*        __restrict__ out)
{
    const int tid  = threadIdx.x;
    const int lane = tid & 63;
    const int wave = tid >> 6;

    double s = 0.0, c = 0.0;
    for (int i = tid; i < BROWS; i += 256) {
        s += row_sum[i];
        c += row_cnt[i];
    }
    #pragma unroll
    for (int off = 32; off > 0; off >>= 1) {
        s += __shfl_down(s, off, 64);
        c += __shfl_down(c, off, 64);
    }
    __shared__ double ls[4], lc[4];
    if (lane == 0) { ls[wave] = s; lc[wave] = c; }
    __syncthreads();
    if (tid == 0) {
        double ts = ls[0] + ls[1] + ls[2] + ls[3];
        double tc = lc[0] + lc[1] + lc[2] + lc[3];
        out[0] = (float)(ts / tc);
    }
}

extern "C" void kernel_launch(void* const* d_in, const int* in_sizes, int n_in,
                              void* d_out, int out_size, void* d_ws, size_t ws_size,
                              hipStream_t stream) {
    const int*   seq    = (const int*)  d_in[0];
    const float* logp   = (const float*)d_in[1];
    const float* value  = (const float*)d_in[2];
    const float* reward = (const float*)d_in[3];
    float* out = (float*)d_out;

    double* row_sum = (double*)d_ws;            // 8192 * 8 B
    double* row_cnt = row_sum + BROWS;          // 8192 * 8 B  (128 KB total)

    row_reduce_kernel<<<BROWS, 256, 0, stream>>>(seq, logp, value, reward,
                                                 row_sum, row_cnt);
    final_reduce_kernel<<<1, 256, 0, stream>>>(row_sum, row_cnt, out);
}